// Round 2
// baseline (930.444 us; speedup 1.0000x reference)
//
#include <hip/hip_runtime.h>
#include <hip/hip_bf16.h>

#define NPTS   32768
#define EEDGES 1048576
#define TOTIT  (EEDGES + NPTS)   // edges + self-loops
#define PTSC   1024              // points per cloud
#define NCLOUD 32
#define CSTR   133               // padded per-cloud stride (floats, odd -> bank spread)
#define PGROW  (NCLOUD * CSTR)   // 4256 floats per partial-accumulator row

// ---------------- encoder: pos[N,3] -> x[N,128] (bf16), 3 tanh layers ----------------
// one wave handles 4 points; lane l owns row l of layer1/2 and rows 2l,2l+1 of layer3
// so the bf16 store is one __hip_bfloat162 per point per lane.
__global__ __launch_bounds__(256) void enc_kernel(
    const float* __restrict__ pos,
    const float* __restrict__ w1, const float* __restrict__ b1,
    const float* __restrict__ w2, const float* __restrict__ b2,
    const float* __restrict__ w3, const float* __restrict__ b3,
    __hip_bfloat16* __restrict__ xb) {
  int wid  = (blockIdx.x * blockDim.x + threadIdx.x) >> 6;
  int lane = threadIdx.x & 63;
  int i0 = wid * 4;
  if (i0 >= NPTS) return;

  float w1a = w1[lane * 3 + 0], w1b = w1[lane * 3 + 1], w1c = w1[lane * 3 + 2];
  float bb1 = b1[lane];

  float h1[4];
#pragma unroll
  for (int p = 0; p < 4; ++p) {
    int i = i0 + p;
    float px = pos[i * 3 + 0], py = pos[i * 3 + 1], pz = pos[i * 3 + 2];
    h1[p] = tanhf(w1a * px + w1b * py + w1c * pz + bb1);
  }

  float bb2 = b2[lane];
  float acc2[4] = {bb2, bb2, bb2, bb2};
  for (int k = 0; k < 64; ++k) {
    float w = w2[lane * 64 + k];
#pragma unroll
    for (int p = 0; p < 4; ++p) acc2[p] += w * __shfl(h1[p], k);
  }
  float h2[4];
#pragma unroll
  for (int p = 0; p < 4; ++p) h2[p] = tanhf(acc2[p]);

  int r0 = 2 * lane, r1 = 2 * lane + 1;
  float bb3a = b3[r0], bb3b = b3[r1];
  float acc3a[4] = {bb3a, bb3a, bb3a, bb3a};
  float acc3b[4] = {bb3b, bb3b, bb3b, bb3b};
  for (int k = 0; k < 64; ++k) {
    float wa = w3[r0 * 64 + k];
    float wb = w3[r1 * 64 + k];
#pragma unroll
    for (int p = 0; p < 4; ++p) {
      float h = __shfl(h2[p], k);
      acc3a[p] += wa * h;
      acc3b[p] += wb * h;
    }
  }
#pragma unroll
  for (int p = 0; p < 4; ++p) {
    int i = i0 + p;
    __hip_bfloat162 o;
    o.x = __float2bfloat16(tanhf(acc3a[p]));
    o.y = __float2bfloat16(tanhf(acc3b[p]));
    *reinterpret_cast<__hip_bfloat162*>(xb + (size_t)i * 128 + r0) = o;
  }
}

// ---------------- degree histogram (4 edges per thread) ----------------
__global__ __launch_bounds__(256) void hist_kernel(const int* __restrict__ ei,
                                                   int* __restrict__ cnt) {
  int t = blockIdx.x * 256 + threadIdx.x;
  const int4* d4 = reinterpret_cast<const int4*>(ei + EEDGES);
  int4 v = d4[t];
  atomicAdd(&cnt[v.x], 1);
  atomicAdd(&cnt[v.y], 1);
  atomicAdd(&cnt[v.z], 1);
  atomicAdd(&cnt[v.w], 1);
}

__global__ __launch_bounds__(256) void invw_kernel(const int* __restrict__ cnt,
                                                   float* __restrict__ invw) {
  int i = blockIdx.x * 256 + threadIdx.x;
  if (i < NPTS) invw[i] = 1.0f / (float)(cnt[i] + 1);
}

// ---------------- edge-parallel gather-accumulate ----------------
// 16 lanes per item (edge or self-loop): lane l owns dims 8l..8l+7 (bf16x8 = dwordx4),
// lanes 0..2 also own pos dims. Contribution w_d * [x[s]; pos[s]-pos[d]] goes to
// LDS accumulator sm[cloud(d)][dim] via ds f32 atomics; block flushes to part_g.
__global__ __launch_bounds__(256) void gather_kernel(
    const __hip_bfloat16* __restrict__ xb, const float* __restrict__ pos,
    const int* __restrict__ ei, const float* __restrict__ invw,
    float* __restrict__ part_g) {
  __shared__ float sm[PGROW];
  for (int i = threadIdx.x; i < PGROW; i += 256) sm[i] = 0.f;
  __syncthreads();

  int wave = threadIdx.x >> 6, lane = threadIdx.x & 63;
  int g = lane >> 4, l = lane & 15;
  int wgid = blockIdx.x * 4 + wave;
  int nw = gridDim.x * 4;
  const ushort* xu = reinterpret_cast<const ushort*>(xb);

  for (int base = wgid * 8; base < TOTIT; base += nw * 8) {
#pragma unroll
    for (int u = 0; u < 2; ++u) {
      int item = base + u * 4 + g;
      int s = 0, d = 0;
      float w = 0.f;
      if (item < TOTIT) {
        if (item < EEDGES) { s = ei[item]; d = ei[item + EEDGES]; }
        else               { s = d = item - EEDGES; }
        w = invw[d];
      }
      uint4 xr = *reinterpret_cast<const uint4*>(xu + (size_t)s * 128 + l * 8);
      float ps = 0.f, pd = 0.f;
      if (l < 3) { ps = pos[s * 3 + l]; pd = pos[d * 3 + l]; }
      int cb = (d >> 10) * CSTR + l * 8;
      float f;
      f = __uint_as_float(xr.x << 16);          atomicAdd(&sm[cb + 0], f * w);
      f = __uint_as_float(xr.x & 0xffff0000u);  atomicAdd(&sm[cb + 1], f * w);
      f = __uint_as_float(xr.y << 16);          atomicAdd(&sm[cb + 2], f * w);
      f = __uint_as_float(xr.y & 0xffff0000u);  atomicAdd(&sm[cb + 3], f * w);
      f = __uint_as_float(xr.z << 16);          atomicAdd(&sm[cb + 4], f * w);
      f = __uint_as_float(xr.z & 0xffff0000u);  atomicAdd(&sm[cb + 5], f * w);
      f = __uint_as_float(xr.w << 16);          atomicAdd(&sm[cb + 6], f * w);
      f = __uint_as_float(xr.w & 0xffff0000u);  atomicAdd(&sm[cb + 7], f * w);
      if (l < 3) atomicAdd(&sm[(d >> 10) * CSTR + 128 + l], (ps - pd) * w);
    }
  }
  __syncthreads();
  float* dst = part_g + (size_t)blockIdx.x * PGROW;
  for (int i = threadIdx.x; i < PGROW; i += 256) dst[i] = sm[i];
}

// ---------------- reduce per-block partials -> Macc[32][CSTR] ----------------
__global__ __launch_bounds__(256) void reduce_kernel(const float* __restrict__ part_g,
                                                     float* __restrict__ Macc, int nb) {
  int idx = blockIdx.x * 256 + threadIdx.x;
  if (idx >= PGROW) return;
  float s0 = 0.f, s1 = 0.f, s2 = 0.f, s3 = 0.f;
  int b = 0;
  for (; b + 3 < nb; b += 4) {
    s0 += part_g[(size_t)(b + 0) * PGROW + idx];
    s1 += part_g[(size_t)(b + 1) * PGROW + idx];
    s2 += part_g[(size_t)(b + 2) * PGROW + idx];
    s3 += part_g[(size_t)(b + 3) * PGROW + idx];
  }
  for (; b < nb; ++b) s0 += part_g[(size_t)b * PGROW + idx];
  Macc[idx] = (s0 + s1) + (s2 + s3);
}

// ---------------- tail: local_nn+global_nn on pooled means + decoder ----------------
__global__ __launch_bounds__(256) void final_kernel(
    const float* __restrict__ Macc,
    const float* __restrict__ loc_w, const float* __restrict__ loc_b,
    const float* __restrict__ glob_w, const float* __restrict__ glob_b,
    const float* __restrict__ d1w, const float* __restrict__ d1b,
    const float* __restrict__ d2w, const float* __restrict__ d2b,
    const float* __restrict__ d3w, const float* __restrict__ d3b,
    float* __restrict__ out) {
  int c = blockIdx.x, t = threadIdx.x;
  __shared__ float m[131];
  __shared__ float tt[256];
  __shared__ float u[384];
  __shared__ float a[256];
  __shared__ float bv[128];

  if (t < 131) m[t] = Macc[c * CSTR + t] * (1.0f / (float)PTSC);
  __syncthreads();

  {
    float acc = loc_b[t];
    for (int k = 0; k < 131; ++k) acc += loc_w[t * 131 + k] * m[k];
    tt[t] = acc;
  }
  __syncthreads();

  for (int j = t; j < 384; j += 256) {
    float acc = glob_b[j];
    for (int k = 0; k < 256; ++k) acc += glob_w[j * 256 + k] * tt[k];
    u[j] = acc;
  }
  __syncthreads();

  {
    float acc = d1b[t];
    for (int k = 0; k < 384; ++k) acc += d1w[t * 384 + k] * u[k];
    a[t] = tanhf(acc);
  }
  __syncthreads();

  if (t < 128) {
    float acc = d2b[t];
    for (int k = 0; k < 256; ++k) acc += d2w[t * 256 + k] * a[k];
    bv[t] = tanhf(acc);
  }
  __syncthreads();

  if (t < 16) {
    float acc = d3b[t];
    for (int k = 0; k < 128; ++k) acc += d3w[t * 128 + k] * bv[k];
    out[c * 16 + t] = acc;
  }
}

extern "C" void kernel_launch(void* const* d_in, const int* in_sizes, int n_in,
                              void* d_out, int out_size, void* d_ws, size_t ws_size,
                              hipStream_t stream) {
  const float* pos    = (const float*)d_in[0];
  const int*   ei     = (const int*)d_in[1];
  const float* enc1_w = (const float*)d_in[2];
  const float* enc1_b = (const float*)d_in[3];
  const float* enc2_w = (const float*)d_in[4];
  const float* enc2_b = (const float*)d_in[5];
  const float* enc3_w = (const float*)d_in[6];
  const float* enc3_b = (const float*)d_in[7];
  const float* loc_w  = (const float*)d_in[8];
  const float* loc_b  = (const float*)d_in[9];
  const float* glob_w = (const float*)d_in[10];
  const float* glob_b = (const float*)d_in[11];
  const float* d1w    = (const float*)d_in[12];
  const float* d1b    = (const float*)d_in[13];
  const float* d2w    = (const float*)d_in[14];
  const float* d2b    = (const float*)d_in[15];
  const float* d3w    = (const float*)d_in[16];
  const float* d3b    = (const float*)d_in[17];
  float* out = (float*)d_out;

  // workspace layout (bytes)
  char* ws = (char*)d_ws;
  __hip_bfloat16* xb = (__hip_bfloat16*)(ws + 0);             // N*128 bf16 = 8,388,608
  int*   cnt   = (int*)  (ws + 8388608);                      // N i32 = 131,072
  float* invw  = (float*)(ws + 8388608 + 131072);             // N f32 = 131,072
  float* Macc  = (float*)(ws + 8388608 + 131072 + 131072);    // PGROW f32 (pad to 17,408)
  size_t fixedEnd = 8388608 + 131072 + 131072 + 17408;        // 8,668,160
  float* part_g = (float*)(ws + fixedEnd);

  // size the gather grid by available workspace (deterministic given ws_size)
  size_t rowBytes = (size_t)PGROW * 4;
  int GB = 1024;
  if (ws_size > fixedEnd) {
    size_t fit = (ws_size - fixedEnd) / rowBytes;
    if (fit < (size_t)GB) GB = (int)fit;
  } else {
    GB = 64;  // should not happen; keep launch valid
  }
  if (GB < 1) GB = 1;

  hipMemsetAsync(cnt, 0, NPTS * sizeof(int), stream);

  hist_kernel<<<EEDGES / 1024, 256, 0, stream>>>(ei, cnt);
  invw_kernel<<<NPTS / 256, 256, 0, stream>>>(cnt, invw);
  enc_kernel<<<NPTS / 16, 256, 0, stream>>>(pos, enc1_w, enc1_b, enc2_w, enc2_b,
                                            enc3_w, enc3_b, xb);
  gather_kernel<<<GB, 256, 0, stream>>>(xb, pos, ei, invw, part_g);
  reduce_kernel<<<(PGROW + 255) / 256, 256, 0, stream>>>(part_g, Macc, GB);
  final_kernel<<<NCLOUD, 256, 0, stream>>>(Macc, loc_w, loc_b, glob_w, glob_b,
                                           d1w, d1b, d2w, d2b, d3w, d3b, out);
}

// Round 3
// 273.011 us; speedup vs baseline: 3.4081x; 3.4081x over previous
//
#include <hip/hip_runtime.h>
#include <hip/hip_bf16.h>

#define NPTS   32768
#define EEDGES 1048576
#define PTSC   1024
#define NCLOUD 32
#define ADIM   132              // padded per-cloud output stride (128 x + 3 pos + pad)
#define MROW   (NCLOUD * ADIM)  // 4224 floats per partial row
#define FXSCALE 16777216.0f     // 2^24 fixed-point for deterministic alpha

// ---------------- encoder: pos[N,3] -> x[N,128] (bf16), 3 tanh layers ----------------
__global__ __launch_bounds__(256) void enc_kernel(
    const float* __restrict__ pos,
    const float* __restrict__ w1, const float* __restrict__ b1,
    const float* __restrict__ w2, const float* __restrict__ b2,
    const float* __restrict__ w3, const float* __restrict__ b3,
    __hip_bfloat16* __restrict__ xb) {
  int wid  = (blockIdx.x * blockDim.x + threadIdx.x) >> 6;
  int lane = threadIdx.x & 63;
  int i0 = wid * 4;
  if (i0 >= NPTS) return;

  float w1a = w1[lane * 3 + 0], w1b = w1[lane * 3 + 1], w1c = w1[lane * 3 + 2];
  float bb1 = b1[lane];

  float h1[4];
#pragma unroll
  for (int p = 0; p < 4; ++p) {
    int i = i0 + p;
    float px = pos[i * 3 + 0], py = pos[i * 3 + 1], pz = pos[i * 3 + 2];
    h1[p] = tanhf(w1a * px + w1b * py + w1c * pz + bb1);
  }

  float bb2 = b2[lane];
  float acc2[4] = {bb2, bb2, bb2, bb2};
  for (int k = 0; k < 64; ++k) {
    float w = w2[lane * 64 + k];
#pragma unroll
    for (int p = 0; p < 4; ++p) acc2[p] += w * __shfl(h1[p], k);
  }
  float h2[4];
#pragma unroll
  for (int p = 0; p < 4; ++p) h2[p] = tanhf(acc2[p]);

  int r0 = 2 * lane, r1 = 2 * lane + 1;
  float bb3a = b3[r0], bb3b = b3[r1];
  float acc3a[4] = {bb3a, bb3a, bb3a, bb3a};
  float acc3b[4] = {bb3b, bb3b, bb3b, bb3b};
  for (int k = 0; k < 64; ++k) {
    float wa = w3[r0 * 64 + k];
    float wb = w3[r1 * 64 + k];
#pragma unroll
    for (int p = 0; p < 4; ++p) {
      float h = __shfl(h2[p], k);
      acc3a[p] += wa * h;
      acc3b[p] += wb * h;
    }
  }
#pragma unroll
  for (int p = 0; p < 4; ++p) {
    int i = i0 + p;
    __hip_bfloat162 o;
    o.x = __float2bfloat16(tanhf(acc3a[p]));
    o.y = __float2bfloat16(tanhf(acc3b[p]));
    *reinterpret_cast<__hip_bfloat162*>(xb + (size_t)i * 128 + r0) = o;
  }
}

// ---------------- degree histogram ----------------
__global__ __launch_bounds__(256) void hist_kernel(const int* __restrict__ ei,
                                                   int* __restrict__ cnt) {
  int t = blockIdx.x * 256 + threadIdx.x;
  const int4* d4 = reinterpret_cast<const int4*>(ei + EEDGES);
  int4 v = d4[t];
  atomicAdd(&cnt[v.x], 1);
  atomicAdd(&cnt[v.y], 1);
  atomicAdd(&cnt[v.z], 1);
  atomicAdd(&cnt[v.w], 1);
}

// invwi[i] = round(2^24 / (deg[i]+1))  (fixed-point inverse weight)
__global__ __launch_bounds__(256) void invwi_kernel(const int* __restrict__ cnt,
                                                    int* __restrict__ invwi) {
  int i = blockIdx.x * 256 + threadIdx.x;
  if (i < NPTS) invwi[i] = (int)rintf(FXSCALE / (float)(cnt[i] + 1));
}

// ---------------- alpha scatter: ai[s*32 + cloud(d)] += invwi[d] ----------------
__global__ __launch_bounds__(256) void ascatter_kernel(const int* __restrict__ ei,
                                                       const int* __restrict__ invwi,
                                                       int* __restrict__ ai) {
  int e = blockIdx.x * 256 + threadIdx.x;
  int s = ei[e];
  int d = ei[e + EEDGES];
  atomicAdd(&ai[s * 32 + (d >> 10)], invwi[d]);
}

// fixed-point -> float, folding in the self-loop diagonal term (in place)
__global__ __launch_bounds__(256) void cvt_kernel(int* __restrict__ ai,
                                                  const int* __restrict__ invwi) {
  int e = blockIdx.x * 256 + threadIdx.x;   // e < NPTS*32
  int s = e >> 5, c = e & 31;
  int v = ai[e];
  if (c == (s >> 10)) v += invwi[s];
  reinterpret_cast<float*>(ai)[e] = (float)v * (1.0f / FXSCALE);
}

// ---------------- contraction: partial[b][c][dim] = sum_{s in chunk} alpha[s][c]*X[s][dim]
// 4 waves/block; wave w owns clouds w*8..w*8+7; lane l owns dims l, 64+l, (l<3:pos l).
__global__ __launch_bounds__(256) void contract_kernel(
    const ushort* __restrict__ xu, const float* __restrict__ pos,
    const float* __restrict__ alpha, float* __restrict__ partial, int chunk) {
  int w = threadIdx.x >> 6, l = threadIdx.x & 63;
  int cw = w * 8;
  int s0 = blockIdx.x * chunk;
  int s1 = min(s0 + chunk, NPTS);

  float a0[8] = {0,0,0,0,0,0,0,0};
  float a1[8] = {0,0,0,0,0,0,0,0};
  float a2[8] = {0,0,0,0,0,0,0,0};

#pragma unroll 2
  for (int s = s0; s < s1; ++s) {
    float f0 = __uint_as_float(((unsigned)xu[(size_t)s * 128 + l]) << 16);
    float f1 = __uint_as_float(((unsigned)xu[(size_t)s * 128 + 64 + l]) << 16);
    float p  = (l < 3) ? pos[s * 3 + l] : 0.f;
    const float* ar = alpha + (size_t)s * 32 + cw;
#pragma unroll
    for (int cc = 0; cc < 8; ++cc) {
      float a = ar[cc];                 // wave-uniform -> scalar load
      a0[cc] += a * f0;
      a1[cc] += a * f1;
      a2[cc] += a * p;
    }
  }

  float* pb = partial + (size_t)blockIdx.x * MROW;
#pragma unroll
  for (int cc = 0; cc < 8; ++cc) {
    pb[(cw + cc) * ADIM + l]      = a0[cc];
    pb[(cw + cc) * ADIM + 64 + l] = a1[cc];
    if (l < 3) pb[(cw + cc) * ADIM + 128 + l] = a2[cc];
  }
}

// ---------------- reduce partials -> Macc[32][ADIM] ----------------
__global__ __launch_bounds__(256) void reduce_kernel(const float* __restrict__ partial,
                                                     float* __restrict__ Macc, int nb) {
  int idx = blockIdx.x * 256 + threadIdx.x;
  if (idx >= MROW) return;
  float s0 = 0.f, s1 = 0.f;
  int b = 0;
  for (; b + 1 < nb; b += 2) {
    s0 += partial[(size_t)b * MROW + idx];
    s1 += partial[(size_t)(b + 1) * MROW + idx];
  }
  if (b < nb) s0 += partial[(size_t)b * MROW + idx];
  Macc[idx] = s0 + s1;
}

// ---------------- tail MLP ----------------
__global__ __launch_bounds__(256) void final_kernel(
    const float* __restrict__ Macc, const float* __restrict__ pos,
    const float* __restrict__ loc_w, const float* __restrict__ loc_b,
    const float* __restrict__ glob_w, const float* __restrict__ glob_b,
    const float* __restrict__ d1w, const float* __restrict__ d1b,
    const float* __restrict__ d2w, const float* __restrict__ d2b,
    const float* __restrict__ d3w, const float* __restrict__ d3b,
    float* __restrict__ out) {
  int c = blockIdx.x, t = threadIdx.x;
  __shared__ float red[3][256];
  __shared__ float m[131];
  __shared__ float tt[256];
  __shared__ float u[384];
  __shared__ float a[256];
  __shared__ float bv[128];

  // sum of pos over this cloud (for the exact pos-part correction)
  float s0 = 0.f, s1 = 0.f, s2 = 0.f;
  for (int i = t; i < PTSC; i += 256) {
    const float* pr = pos + ((size_t)c * PTSC + i) * 3;
    s0 += pr[0]; s1 += pr[1]; s2 += pr[2];
  }
  red[0][t] = s0; red[1][t] = s1; red[2][t] = s2;
  __syncthreads();
  for (int off = 128; off > 0; off >>= 1) {
    if (t < off) {
      red[0][t] += red[0][t + off];
      red[1][t] += red[1][t + off];
      red[2][t] += red[2][t + off];
    }
    __syncthreads();
  }

  if (t < 128)                 m[t] = Macc[c * ADIM + t] * (1.0f / (float)PTSC);
  else if (t < 131)            m[t] = (Macc[c * ADIM + t] - red[t - 128][0]) * (1.0f / (float)PTSC);
  __syncthreads();

  {
    float acc = loc_b[t];
    for (int k = 0; k < 131; ++k) acc += loc_w[t * 131 + k] * m[k];
    tt[t] = acc;
  }
  __syncthreads();

  for (int j = t; j < 384; j += 256) {
    float acc = glob_b[j];
    for (int k = 0; k < 256; ++k) acc += glob_w[j * 256 + k] * tt[k];
    u[j] = acc;
  }
  __syncthreads();

  {
    float acc = d1b[t];
    for (int k = 0; k < 384; ++k) acc += d1w[t * 384 + k] * u[k];
    a[t] = tanhf(acc);
  }
  __syncthreads();

  if (t < 128) {
    float acc = d2b[t];
    for (int k = 0; k < 256; ++k) acc += d2w[t * 256 + k] * a[k];
    bv[t] = tanhf(acc);
  }
  __syncthreads();

  if (t < 16) {
    float acc = d3b[t];
    for (int k = 0; k < 128; ++k) acc += d3w[t * 128 + k] * bv[k];
    out[c * 16 + t] = acc;
  }
}

extern "C" void kernel_launch(void* const* d_in, const int* in_sizes, int n_in,
                              void* d_out, int out_size, void* d_ws, size_t ws_size,
                              hipStream_t stream) {
  const float* pos    = (const float*)d_in[0];
  const int*   ei     = (const int*)d_in[1];
  const float* enc1_w = (const float*)d_in[2];
  const float* enc1_b = (const float*)d_in[3];
  const float* enc2_w = (const float*)d_in[4];
  const float* enc2_b = (const float*)d_in[5];
  const float* enc3_w = (const float*)d_in[6];
  const float* enc3_b = (const float*)d_in[7];
  const float* loc_w  = (const float*)d_in[8];
  const float* loc_b  = (const float*)d_in[9];
  const float* glob_w = (const float*)d_in[10];
  const float* glob_b = (const float*)d_in[11];
  const float* d1w    = (const float*)d_in[12];
  const float* d1b    = (const float*)d_in[13];
  const float* d2w    = (const float*)d_in[14];
  const float* d2b    = (const float*)d_in[15];
  const float* d3w    = (const float*)d_in[16];
  const float* d3b    = (const float*)d_in[17];
  float* out = (float*)d_out;

  // workspace layout (bytes)
  char* ws = (char*)d_ws;
  __hip_bfloat16* xb = (__hip_bfloat16*)(ws + 0);       // 8,388,608
  int*   ai    = (int*)  (ws + 8388608);                // N*32 i32/f32 = 4,194,304
  int*   cnt   = (int*)  (ws + 8388608 + 4194304);      // 131,072
  int*   invwi = (int*)  (ws + 8388608 + 4194304 + 131072);  // 131,072
  float* Macc  = (float*)(ws + 8388608 + 4194304 + 131072 + 131072);  // 17,408 (padded)
  size_t fixedEnd = 8388608 + 4194304 + 131072 + 131072 + 17408;      // 12,862,464
  float* partial = (float*)(ws + fixedEnd);

  // contraction block count sized by available workspace (deterministic)
  size_t rowBytes = (size_t)MROW * 4;
  int NBLK = 256;
  if (ws_size > fixedEnd) {
    size_t fit = (ws_size - fixedEnd) / rowBytes;
    if (fit < (size_t)NBLK) NBLK = (int)fit;
  } else {
    NBLK = 1;
  }
  if (NBLK < 1) NBLK = 1;
  int chunk = (NPTS + NBLK - 1) / NBLK;

  hipMemsetAsync(cnt, 0, NPTS * sizeof(int), stream);
  hipMemsetAsync(ai, 0, NPTS * 32 * sizeof(int), stream);

  hist_kernel<<<EEDGES / 1024, 256, 0, stream>>>(ei, cnt);
  invwi_kernel<<<NPTS / 256, 256, 0, stream>>>(cnt, invwi);
  enc_kernel<<<NPTS / 16, 256, 0, stream>>>(pos, enc1_w, enc1_b, enc2_w, enc2_b,
                                            enc3_w, enc3_b, xb);
  ascatter_kernel<<<EEDGES / 256, 256, 0, stream>>>(ei, invwi, ai);
  cvt_kernel<<<NPTS * 32 / 256, 256, 0, stream>>>(ai, invwi);
  contract_kernel<<<NBLK, 256, 0, stream>>>((const ushort*)xb, pos,
                                            (const float*)ai, partial, chunk);
  reduce_kernel<<<(MROW + 255) / 256, 256, 0, stream>>>(partial, Macc, NBLK);
  final_kernel<<<NCLOUD, 256, 0, stream>>>(Macc, pos, loc_w, loc_b, glob_w, glob_b,
                                           d1w, d1b, d2w, d2b, d3w, d3b, out);
}

// Round 5
// 264.269 us; speedup vs baseline: 3.5208x; 1.0331x over previous
//
#include <hip/hip_runtime.h>
#include <hip/hip_bf16.h>

#define NPTS   32768
#define EEDGES 1048576
#define TOTIT  (EEDGES + NPTS)
#define PTSC   1024
#define NCLOUD 32
#define ADIM   132              // per-cloud stride: 128 x + 3 pos + pad
#define MROW   (NCLOUD * ADIM)  // 4224
#define NBLK   256              // contract partial blocks (fixed, deterministic)
#define CHUNK  (NPTS / NBLK)    // 128
#define FXSCALE 16777216.0f     // 2^24

// ---------------- weight transpose prep: dst[c*R + r] = src[r*C + c] ----------------
__global__ __launch_bounds__(256) void prep_kernel(
    const float* __restrict__ w2, const float* __restrict__ w3,
    const float* __restrict__ locw, const float* __restrict__ globw,
    const float* __restrict__ d1w, const float* __restrict__ d2w,
    const float* __restrict__ d3w,
    float* __restrict__ w2T, float* __restrict__ w3T,
    float* __restrict__ locT, float* __restrict__ globT,
    float* __restrict__ d1T, float* __restrict__ d2T, float* __restrict__ d3T) {
  int idx = blockIdx.x * 256 + threadIdx.x;
  const float* src; float* dst; int R, C;
  if (idx < 4096)        { src = w2;   dst = w2T;   R = 64;  C = 64;  }
  else if (idx < 12288)  { src = w3;   dst = w3T;   R = 128; C = 64;  idx -= 4096; }
  else if (idx < 45824)  { src = locw; dst = locT;  R = 256; C = 131; idx -= 12288; }
  else if (idx < 144128) { src = globw;dst = globT; R = 384; C = 256; idx -= 45824; }
  else if (idx < 242432) { src = d1w;  dst = d1T;   R = 256; C = 384; idx -= 144128; }
  else if (idx < 275200) { src = d2w;  dst = d2T;   R = 128; C = 256; idx -= 242432; }
  else                   { src = d3w;  dst = d3T;   R = 16;  C = 128; idx -= 275200; }
  int c = idx / R, r = idx % R;
  dst[idx] = src[r * C + c];
}

// ---------------- encoder: pos[N,3] -> x[N,128] (bf16) ----------------
// wave = 4 points; lane owns layer1/2 row `lane`, layer3 rows 2l,2l+1.
__global__ __launch_bounds__(256) void enc_kernel(
    const float* __restrict__ pos,
    const float* __restrict__ w1, const float* __restrict__ b1,
    const float* __restrict__ w2T, const float* __restrict__ b2,
    const float* __restrict__ w3T, const float* __restrict__ b3,
    __hip_bfloat16* __restrict__ xb) {
  int wid  = (blockIdx.x * blockDim.x + threadIdx.x) >> 6;
  int lane = threadIdx.x & 63;
  int i0 = wid * 4;
  if (i0 >= NPTS) return;

  float w1a = w1[lane * 3 + 0], w1b = w1[lane * 3 + 1], w1c = w1[lane * 3 + 2];
  float bb1 = b1[lane];

  float h1[4];
#pragma unroll
  for (int p = 0; p < 4; ++p) {
    int i = i0 + p;
    float px = pos[i * 3 + 0], py = pos[i * 3 + 1], pz = pos[i * 3 + 2];
    h1[p] = tanhf(w1a * px + w1b * py + w1c * pz + bb1);
  }

  float bb2 = b2[lane];
  float acc2[4] = {bb2, bb2, bb2, bb2};
#pragma unroll 8
  for (int k = 0; k < 64; ++k) {
    float w = w2T[k * 64 + lane];          // coalesced
#pragma unroll
    for (int p = 0; p < 4; ++p) acc2[p] += w * __shfl(h1[p], k);
  }
  float h2[4];
#pragma unroll
  for (int p = 0; p < 4; ++p) h2[p] = tanhf(acc2[p]);

  int r0 = 2 * lane;
  float bb3a = b3[r0], bb3b = b3[r0 + 1];
  float acc3a[4] = {bb3a, bb3a, bb3a, bb3a};
  float acc3b[4] = {bb3b, bb3b, bb3b, bb3b};
#pragma unroll 8
  for (int k = 0; k < 64; ++k) {
    float2 w = *reinterpret_cast<const float2*>(w3T + k * 128 + r0);  // coalesced
#pragma unroll
    for (int p = 0; p < 4; ++p) {
      float h = __shfl(h2[p], k);
      acc3a[p] += w.x * h;
      acc3b[p] += w.y * h;
    }
  }
#pragma unroll
  for (int p = 0; p < 4; ++p) {
    int i = i0 + p;
    __hip_bfloat162 o;
    o.x = __float2bfloat16(tanhf(acc3a[p]));
    o.y = __float2bfloat16(tanhf(acc3b[p]));
    *reinterpret_cast<__hip_bfloat162*>(xb + (size_t)i * 128 + r0) = o;
  }
}

// ---------------- degree histogram ----------------
__global__ __launch_bounds__(256) void hist_kernel(const int* __restrict__ ei,
                                                   int* __restrict__ cnt) {
  int t = blockIdx.x * 256 + threadIdx.x;
  const int4* d4 = reinterpret_cast<const int4*>(ei + EEDGES);
  int4 v = d4[t];
  atomicAdd(&cnt[v.x], 1);
  atomicAdd(&cnt[v.y], 1);
  atomicAdd(&cnt[v.z], 1);
  atomicAdd(&cnt[v.w], 1);
}

__global__ __launch_bounds__(256) void invwi_kernel(const int* __restrict__ cnt,
                                                    int* __restrict__ invwi) {
  int i = blockIdx.x * 256 + threadIdx.x;
  if (i < NPTS) invwi[i] = (int)rintf(FXSCALE / (float)(cnt[i] + 1));
}

// ---------------- alpha scatter incl. self-loops ----------------
__global__ __launch_bounds__(256) void ascatter_kernel(const int* __restrict__ ei,
                                                       const int* __restrict__ invwi,
                                                       int* __restrict__ ai) {
  int e = blockIdx.x * 256 + threadIdx.x;   // e < TOTIT
  int s, d;
  if (e < EEDGES) { s = ei[e]; d = ei[e + EEDGES]; }
  else            { s = d = e - EEDGES; }
  atomicAdd(&ai[s * 32 + (d >> 10)], invwi[d]);
}

// ---------------- contraction: partial[b][c][dim] = sum_s alpha[s][c]*X[s][dim]
// 4 waves/block; wave w owns clouds w*8..w*8+7; lane l owns x dims 2l,2l+1 (+pos l if l<3).
__global__ __launch_bounds__(256) void contract_kernel(
    const ushort* __restrict__ xu, const float* __restrict__ pos,
    const int* __restrict__ ai, float* __restrict__ partial) {
  int w = threadIdx.x >> 6, l = threadIdx.x & 63;
  int cw = w * 8;
  int s0 = blockIdx.x * CHUNK;
  int s1 = s0 + CHUNK;

  float a0[8] = {0,0,0,0,0,0,0,0};
  float a1[8] = {0,0,0,0,0,0,0,0};
  float a2[8] = {0,0,0,0,0,0,0,0};

#pragma unroll 2
  for (int s = s0; s < s1; ++s) {
    unsigned xr = *reinterpret_cast<const unsigned*>(xu + (size_t)s * 128 + 2 * l);
    float f0 = __uint_as_float(xr << 16);
    float f1 = __uint_as_float(xr & 0xffff0000u);
    float p  = (l < 3) ? pos[s * 3 + l] : 0.f;
    const int4* ar = reinterpret_cast<const int4*>(ai + (size_t)s * 32 + cw);
    int4 A0 = ar[0], A1 = ar[1];
    float af[8] = {(float)A0.x, (float)A0.y, (float)A0.z, (float)A0.w,
                   (float)A1.x, (float)A1.y, (float)A1.z, (float)A1.w};
#pragma unroll
    for (int cc = 0; cc < 8; ++cc) {
      a0[cc] += af[cc] * f0;
      a1[cc] += af[cc] * f1;
      a2[cc] += af[cc] * p;
    }
  }

  const float SC = 1.0f / FXSCALE;
  float* pb = partial + (size_t)blockIdx.x * MROW;
#pragma unroll
  for (int cc = 0; cc < 8; ++cc) {
    pb[(cw + cc) * ADIM + 2 * l]     = a0[cc] * SC;
    pb[(cw + cc) * ADIM + 2 * l + 1] = a1[cc] * SC;
    if (l < 3) pb[(cw + cc) * ADIM + 128 + l] = a2[cc] * SC;
  }
}

// ---------------- reduce partials -> Macc[32][ADIM] ----------------
__global__ __launch_bounds__(256) void reduce_kernel(const float* __restrict__ partial,
                                                     float* __restrict__ Macc) {
  int idx = blockIdx.x * 256 + threadIdx.x;
  if (idx >= MROW) return;
  float s0 = 0.f, s1 = 0.f;
  for (int b = 0; b < NBLK; b += 2) {
    s0 += partial[(size_t)b * MROW + idx];
    s1 += partial[(size_t)(b + 1) * MROW + idx];
  }
  Macc[idx] = s0 + s1;
}

// ---------------- tail MLP (transposed weights, coalesced) ----------------
__global__ __launch_bounds__(256) void final_kernel(
    const float* __restrict__ Macc, const float* __restrict__ pos,
    const float* __restrict__ locT, const float* __restrict__ loc_b,
    const float* __restrict__ globT, const float* __restrict__ glob_b,
    const float* __restrict__ d1T, const float* __restrict__ d1b,
    const float* __restrict__ d2T, const float* __restrict__ d2b,
    const float* __restrict__ d3T, const float* __restrict__ d3b,
    float* __restrict__ out) {
  int c = blockIdx.x, t = threadIdx.x;
  __shared__ float red[3][256];
  __shared__ float m[131];
  __shared__ float tt[256];
  __shared__ float u[384];
  __shared__ float a[256];
  __shared__ float bv[128];

  float s0 = 0.f, s1 = 0.f, s2 = 0.f;
  for (int i = t; i < PTSC; i += 256) {
    const float* pr = pos + ((size_t)c * PTSC + i) * 3;
    s0 += pr[0]; s1 += pr[1]; s2 += pr[2];
  }
  red[0][t] = s0; red[1][t] = s1; red[2][t] = s2;
  __syncthreads();
  for (int off = 128; off > 0; off >>= 1) {
    if (t < off) {
      red[0][t] += red[0][t + off];
      red[1][t] += red[1][t + off];
      red[2][t] += red[2][t + off];
    }
    __syncthreads();
  }

  if (t < 128)      m[t] = Macc[c * ADIM + t] * (1.0f / (float)PTSC);
  else if (t < 131) m[t] = (Macc[c * ADIM + t] - red[t - 128][0]) * (1.0f / (float)PTSC);
  __syncthreads();

  {
    float acc = loc_b[t];
    for (int k = 0; k < 131; ++k) acc += locT[k * 256 + t] * m[k];
    tt[t] = acc;
  }
  __syncthreads();

  for (int j = t; j < 384; j += 256) {
    float acc = glob_b[j];
    for (int k = 0; k < 256; ++k) acc += globT[k * 384 + j] * tt[k];
    u[j] = acc;
  }
  __syncthreads();

  {
    float acc = d1b[t];
    for (int k = 0; k < 384; ++k) acc += d1T[k * 256 + t] * u[k];
    a[t] = tanhf(acc);
  }
  __syncthreads();

  if (t < 128) {
    float acc = d2b[t];
    for (int k = 0; k < 256; ++k) acc += d2T[k * 128 + t] * a[k];
    bv[t] = tanhf(acc);
  }
  __syncthreads();

  if (t < 16) {
    float acc = d3b[t];
    for (int k = 0; k < 128; ++k) acc += d3T[k * 16 + t] * bv[k];
    out[c * 16 + t] = acc;
  }
}

extern "C" void kernel_launch(void* const* d_in, const int* in_sizes, int n_in,
                              void* d_out, int out_size, void* d_ws, size_t ws_size,
                              hipStream_t stream) {
  const float* pos    = (const float*)d_in[0];
  const int*   ei     = (const int*)d_in[1];
  const float* enc1_w = (const float*)d_in[2];
  const float* enc1_b = (const float*)d_in[3];
  const float* enc2_w = (const float*)d_in[4];
  const float* enc2_b = (const float*)d_in[5];
  const float* enc3_w = (const float*)d_in[6];
  const float* enc3_b = (const float*)d_in[7];
  const float* loc_w  = (const float*)d_in[8];
  const float* loc_b  = (const float*)d_in[9];
  const float* glob_w = (const float*)d_in[10];
  const float* glob_b = (const float*)d_in[11];
  const float* d1w    = (const float*)d_in[12];
  const float* d1b    = (const float*)d_in[13];
  const float* d2w    = (const float*)d_in[14];
  const float* d2b    = (const float*)d_in[15];
  const float* d3w    = (const float*)d_in[16];
  const float* d3b    = (const float*)d_in[17];
  float* out = (float*)d_out;

  // workspace layout (bytes, all 256B-aligned)
  char* ws = (char*)d_ws;
  size_t o = 0;
  __hip_bfloat16* xb = (__hip_bfloat16*)(ws + o); o += 8388608;     // N*128 bf16
  int*   ai    = (int*)  (ws + o); o += 4194304;                    // N*32 i32
  int*   cnt   = (int*)  (ws + o); o += 131072;
  int*   invwi = (int*)  (ws + o); o += 131072;
  float* Macc  = (float*)(ws + o); o += 17408;                      // MROW padded
  float* w2T   = (float*)(ws + o); o += 16384;
  float* w3T   = (float*)(ws + o); o += 32768;
  float* locT  = (float*)(ws + o); o += 134144;
  float* globT = (float*)(ws + o); o += 393216;
  float* d1T   = (float*)(ws + o); o += 393216;
  float* d2T   = (float*)(ws + o); o += 131072;
  float* d3T   = (float*)(ws + o); o += 8192;
  float* partial = (float*)(ws + o);                                // NBLK*MROW f32 = 4,325,376
  (void)ws_size;

  hipMemsetAsync(cnt, 0, NPTS * sizeof(int), stream);
  hipMemsetAsync(ai, 0, NPTS * 32 * sizeof(int), stream);

  prep_kernel<<<1083, 256, 0, stream>>>(enc2_w, enc3_w, loc_w, glob_w, d1w, d2w, d3w,
                                        w2T, w3T, locT, globT, d1T, d2T, d3T);
  hist_kernel<<<EEDGES / 1024, 256, 0, stream>>>(ei, cnt);
  invwi_kernel<<<NPTS / 256, 256, 0, stream>>>(cnt, invwi);
  enc_kernel<<<NPTS / 16, 256, 0, stream>>>(pos, enc1_w, enc1_b, w2T, enc2_b,
                                            w3T, enc3_b, xb);
  ascatter_kernel<<<TOTIT / 256, 256, 0, stream>>>(ei, invwi, ai);
  contract_kernel<<<NBLK, 256, 0, stream>>>((const ushort*)xb, pos, ai, partial);
  reduce_kernel<<<(MROW + 255) / 256, 256, 0, stream>>>(partial, Macc);
  final_kernel<<<NCLOUD, 256, 0, stream>>>(Macc, pos, locT, loc_b, globT, glob_b,
                                           d1T, d1b, d2T, d2b, d3T, d3b, out);
}